// Round 6
// baseline (374.960 us; speedup 1.0000x reference)
//
#include <hip/hip_runtime.h>
#include <hip/hip_bf16.h>

typedef unsigned short u16;
typedef __attribute__((ext_vector_type(8))) short short8;
typedef __attribute__((ext_vector_type(8))) unsigned short u16x8;
typedef __attribute__((ext_vector_type(4))) float f32x4;

#define H_DIM 2048
#define EI_DIM 1024
#define NEXP 8

template <int V> struct IC { static constexpr int value = V; };

__device__ __forceinline__ u16 f2bf(float f) {
  __hip_bfloat16 h = __float2bfloat16(f);
  return __builtin_bit_cast(unsigned short, h);
}

__device__ __forceinline__ void load_lds16(const void* g, void* lds) {
  __builtin_amdgcn_global_load_lds(
      (const __attribute__((address_space(1))) unsigned int*)g,
      (__attribute__((address_space(3))) unsigned int*)lds, 16, 0, 0);
}

// ---------------- routing ----------------
__global__ void hist_kernel(const int* __restrict__ pid, int* __restrict__ hist) {
  int seg = blockIdx.x, lane = threadIdx.x;
  int eid = pid[seg * 64 + lane] & 7;
#pragma unroll
  for (int e = 0; e < NEXP; ++e) {
    unsigned long long m = __ballot(eid == e);
    if (lane == 0) hist[e * 256 + seg] = __popcll(m);
  }
}

__global__ void scan_kernel(const int* __restrict__ hist, int* __restrict__ base,
                            int* __restrict__ offcnt, int T) {
  __shared__ int lds[256];
  int tid = threadIdx.x;
  int v[8], s = 0;
#pragma unroll
  for (int j = 0; j < 8; ++j) { v[j] = hist[tid * 8 + j]; s += v[j]; }
  lds[tid] = s;
  __syncthreads();
  for (int d = 1; d < 256; d <<= 1) {
    int t = (tid >= d) ? lds[tid - d] : 0;
    __syncthreads();
    lds[tid] += t;
    __syncthreads();
  }
  int run = lds[tid] - s;
#pragma unroll
  for (int j = 0; j < 8; ++j) { base[tid * 8 + j] = run; run += v[j]; }
  __syncthreads();
  if (tid < NEXP) {
    int o = base[tid * 256];
    int nx = (tid < NEXP - 1) ? base[(tid + 1) * 256] : T;
    offcnt[tid] = o;
    offcnt[8 + tid] = nx - o;
  }
}

// order: expert-ordered slot -> token ; pos: token -> slot (inverse)
__global__ void rank_kernel(const int* __restrict__ pid, const int* __restrict__ base,
                            int* __restrict__ order, int* __restrict__ pos) {
  int seg = blockIdx.x, lane = threadIdx.x;
  int t = seg * 64 + lane;
  int eid = pid[t] & 7;
  unsigned long long below = (1ull << lane) - 1ull;
#pragma unroll
  for (int e = 0; e < NEXP; ++e) {
    unsigned long long m = __ballot(eid == e);
    if (eid == e) {
      int r = __popcll(m & below);
      int g = base[e * 256 + seg] + r;
      order[g] = t;
      pos[t] = g;
    }
  }
}

// ---------------- weight transpose + fp32->bf16 ----------------
__global__ __launch_bounds__(256) void transpose_bf16(const float* __restrict__ in,
                                                      u16* __restrict__ out, int R, int C) {
  __shared__ u16 tile[64][65];
  int nbr = R >> 6, nbc = C >> 6;
  int per_e = nbr * nbc;
  int bx = blockIdx.x;
  int e = bx / per_e, rem = bx % per_e;
  int tr = rem % nbr, tc = rem / nbr;
  const float* ine = in + (size_t)e * R * C;
  u16* oute = out + (size_t)e * R * C;
  int r0 = tr * 64, c0 = tc * 64;
  int tid = threadIdx.x;
  int lrow = tid >> 4, lc4 = (tid & 15) * 4;
#pragma unroll
  for (int p = 0; p < 4; ++p) {
    int rl = p * 16 + lrow;
    float4 v = *(const float4*)&ine[(size_t)(r0 + rl) * C + c0 + lc4];
    tile[rl][lc4 + 0] = f2bf(v.x);
    tile[rl][lc4 + 1] = f2bf(v.y);
    tile[rl][lc4 + 2] = f2bf(v.z);
    tile[rl][lc4 + 3] = f2bf(v.w);
  }
  __syncthreads();
#pragma unroll
  for (int q = 0; q < 16; ++q) {
    int idx = q * 256 + tid;
    int jr = idx >> 6, hc = idx & 63;
    oute[(size_t)(c0 + jr) * R + r0 + hc] = tile[hc][jr];
  }
}

// ---------------- gather + convert x ----------------
__global__ __launch_bounds__(256) void gather_x(const float* __restrict__ x,
                                                const int* __restrict__ order,
                                                u16* __restrict__ xg) {
  int g = blockIdx.x;
  int t = order[g];
  const float* src = x + (size_t)t * H_DIM;
  u16* dst = xg + (size_t)g * H_DIM;
  int c = threadIdx.x * 8;
  float4 a = *(const float4*)&src[c];
  float4 b = *(const float4*)&src[c + 4];
  u16x8 v;
  v[0] = f2bf(a.x); v[1] = f2bf(a.y); v[2] = f2bf(a.z); v[3] = f2bf(a.w);
  v[4] = f2bf(b.x); v[5] = f2bf(b.y); v[6] = f2bf(b.z); v[7] = f2bf(b.w);
  *(u16x8*)&dst[c] = v;
}

// ---------------- unscatter: out[t] = outg[pos[t]] (coalesced write) ----------------
__global__ __launch_bounds__(256) void unscatter_kernel(const float* __restrict__ outg,
                                                        const int* __restrict__ pos,
                                                        float* __restrict__ out) {
  int t = blockIdx.x;
  const float4* src = (const float4*)(outg + (size_t)pos[t] * H_DIM);
  float4* dst = (float4*)(out + (size_t)t * H_DIM);
  int i = threadIdx.x;
  dst[i] = src[i];
  dst[i + 256] = src[i + 256];
}

// ---------------- 256x256 8-phase GEMM body, persistent expert-aligned grid ----------------
// grid = 512: XCD x <-> expert x (chunked swizzle); block loops its expert's
// padded item space (64 slots x 8 strides) -> balanced case = 1 real tile/block.
// KIND 0: gu GEMM, gate/up paired cols, fused silu*up -> inter (bf16)
// KIND 1: down GEMM, CONTIGUOUS expert-ordered fp32 write to outg (no scatter)
template <int KTOT, int KIND>
__device__ __forceinline__ void gemm8_body(
    const u16* __restrict__ A, const u16* __restrict__ Bmat, void* __restrict__ outp,
    const int* __restrict__ offcnt, int T) {
  constexpr int NK = KTOT / 64;  // even
  constexpr int ASTR = (KIND == 0) ? H_DIM : EI_DIM;
  constexpr int BSTR = ASTR;
  constexpr size_t BEXP = (size_t)2048 * BSTR;
  __shared__ u16 As[2][2][8192];
  __shared__ u16 Bs[2][2][8192];

  int nwg = gridDim.x;  // 512
  int bid = blockIdx.x;
  int bx = (bid & 7) * (nwg >> 3) + (bid >> 3);  // XCD-chunked, bijective
  int e = bx >> 6;                               // 64 slots per expert
  int s = bx & 63;
  int off = offcnt[e], cnt = offcnt[8 + e];
  const u16* Be = Bmat + (size_t)e * BEXP;

  int tid = threadIdx.x, w = tid >> 6, l = tid & 63;
  int wm = w >> 2, wn = w & 3, lr = l & 15, lg = l >> 4;
  int cidx = (lg ^ ((lr >> 1) & 3)) * 8;  // swizzled 8-elem chunk for ds_read
  int aRow0 = wm * 128 + lr;
  int bRow0 = wn * 64 + lr;
  int sr[2], sc[2];
#pragma unroll
  for (int j = 0; j < 2; ++j) {
    sr[j] = j * 128 + (tid >> 2);
    int c = tid & 3;
    sc[j] = (c ^ ((sr[j] >> 1) & 3)) * 8;
  }

#pragma unroll 1
  for (int it = s; it < 512; it += 64) {
    int mt = it >> 3, nt = it & 7;
    if (mt * 256 >= cnt) continue;

    const u16* aSrc[2];
    const u16* bSrc[2];
#pragma unroll
    for (int j = 0; j < 2; ++j) {
      int r = sr[j];
      int grow = min(off + mt * 256 + r, T - 1);
      aSrc[j] = A + (size_t)grow * ASTR + sc[j];
      int n;
      if (KIND == 0) {
        int q = r >> 4, rr = r & 15;  // pair gate/up at wave granularity
        n = ((q & 2) ? EI_DIM : 0) + nt * 128 + ((q >> 2) << 5) + ((q & 1) << 4) + rr;
      } else {
        n = nt * 256 + r;
      }
      bSrc[j] = Be + (size_t)n * BSTR + sc[j];
    }

    auto stageA = [&](int kt, int kh, int buf) {
#pragma unroll
      for (int j = 0; j < 2; ++j)
        load_lds16(aSrc[j] + kt * 64 + kh * 32, &As[buf][kh][j * 4096 + w * 512]);
    };
    auto stageB = [&](int kt, int kh, int buf) {
#pragma unroll
      for (int j = 0; j < 2; ++j)
        load_lds16(bSrc[j] + kt * 64 + kh * 32, &Bs[buf][kh][j * 4096 + w * 512]);
    };

    short8 av[4], bv[4];
    auto loadA4 = [&](int buf, int kh, int h) {
#pragma unroll
      for (int mm = 0; mm < 4; ++mm)
        av[mm] = *(const short8*)&As[buf][kh][(aRow0 + (h * 4 + mm) * 16) * 32 + cidx];
    };
    auto loadB4 = [&](int buf, int kh) {
#pragma unroll
      for (int nn = 0; nn < 4; ++nn)
        bv[nn] = *(const short8*)&Bs[buf][kh][(bRow0 + nn * 16) * 32 + cidx];
    };

    f32x4 acc[8][4];
#pragma unroll
    for (int m = 0; m < 8; ++m)
#pragma unroll
      for (int nn = 0; nn < 4; ++nn) acc[m][nn] = {0.f, 0.f, 0.f, 0.f};

    auto MFMA_H = [&](auto HC) {
      constexpr int h = decltype(HC)::value;
      __builtin_amdgcn_s_setprio(1);
#pragma unroll
      for (int mm = 0; mm < 4; ++mm)
#pragma unroll
        for (int nn = 0; nn < 4; ++nn)
          acc[h * 4 + mm][nn] =
              __builtin_amdgcn_mfma_f32_16x16x32_bf16(av[mm], bv[nn], acc[h * 4 + mm][nn], 0, 0, 0);
      __builtin_amdgcn_s_setprio(0);
    };

    // protect LDS against previous iteration's readers
    __syncthreads();

    // ---- prologue: tile0 fully + tile1 {Bk0, Ak0, Bk1} ----
    stageA(0, 0, 0); stageB(0, 0, 0); stageA(0, 1, 0); stageB(0, 1, 0);
    stageB(1, 0, 1); stageA(1, 0, 1); stageB(1, 1, 1);
    asm volatile("s_waitcnt vmcnt(6)" ::: "memory");
    __builtin_amdgcn_s_barrier();
    __builtin_amdgcn_sched_barrier(0);

    auto TILE = [&](int t, auto BC) {
      constexpr int b = decltype(BC)::value;
      constexpr int bn = b ^ 1;
      // p1
      loadA4(b, 0, 0);
      loadB4(b, 0);
      stageA(t + 1, 1, bn);
      __builtin_amdgcn_s_barrier();
      MFMA_H(IC<0>{});
      __builtin_amdgcn_s_barrier();
      __builtin_amdgcn_sched_barrier(0);
      // p2
      loadA4(b, 0, 1);
      stageB(t + 2, 0, b);
      __builtin_amdgcn_s_barrier();
      MFMA_H(IC<1>{});
      __builtin_amdgcn_s_barrier();
      __builtin_amdgcn_sched_barrier(0);
      // p3
      loadA4(b, 1, 0);
      loadB4(b, 1);
      stageA(t + 2, 0, b);
      __builtin_amdgcn_s_barrier();
      MFMA_H(IC<0>{});
      __builtin_amdgcn_s_barrier();
      __builtin_amdgcn_sched_barrier(0);
      // p4
      loadA4(b, 1, 1);
      stageB(t + 2, 1, b);
      __builtin_amdgcn_s_barrier();
      MFMA_H(IC<1>{});
      asm volatile("s_waitcnt vmcnt(6)" ::: "memory");
      __builtin_amdgcn_s_barrier();
      __builtin_amdgcn_sched_barrier(0);
    };

#pragma unroll 1
    for (int t = 0; t < NK - 3; t += 2) {
      TILE(t, IC<0>{});
      TILE(t + 1, IC<1>{});
    }

    // ---- tail: tile NK-2 (stages only A(NK-1,k1)), drain, tile NK-1 ----
    {
      loadA4(0, 0, 0);
      loadB4(0, 0);
      stageA(NK - 1, 1, 1);
      MFMA_H(IC<0>{});
      loadA4(0, 0, 1);
      MFMA_H(IC<1>{});
      loadA4(0, 1, 0);
      loadB4(0, 1);
      MFMA_H(IC<0>{});
      loadA4(0, 1, 1);
      MFMA_H(IC<1>{});
      asm volatile("s_waitcnt vmcnt(0)" ::: "memory");
      __builtin_amdgcn_s_barrier();
      __builtin_amdgcn_sched_barrier(0);
      loadA4(1, 0, 0);
      loadB4(1, 0);
      MFMA_H(IC<0>{});
      loadA4(1, 0, 1);
      MFMA_H(IC<1>{});
      loadA4(1, 1, 0);
      loadB4(1, 1);
      MFMA_H(IC<0>{});
      loadA4(1, 1, 1);
      MFMA_H(IC<1>{});
    }

    // ---- epilogue ----
    if (KIND == 0) {
      u16* inter = (u16*)outp;
#pragma unroll
      for (int m = 0; m < 8; ++m)
#pragma unroll
        for (int nn = 0; nn < 2; ++nn) {
          f32x4 g = acc[m][nn], u = acc[m][nn + 2];
          int icol = nt * 128 + wn * 32 + nn * 16 + lr;
#pragma unroll
          for (int j = 0; j < 4; ++j) {
            int r = wm * 128 + m * 16 + lg * 4 + j;
            int grow = mt * 256 + r;
            if (grow < cnt) {
              float gv = g[j];
              float val = (gv / (1.f + __expf(-gv))) * u[j];
              inter[(size_t)(off + grow) * EI_DIM + icol] = f2bf(val);
            }
          }
        }
    } else {
      // contiguous expert-ordered write: outg[off+grow][nt*256 + c]
      float* outg = (float*)outp;
      float* lf = (float*)&As[0][0][0];
#pragma unroll
      for (int m = 0; m < 8; ++m) {
        __syncthreads();
#pragma unroll
        for (int nn = 0; nn < 4; ++nn)
#pragma unroll
          for (int j = 0; j < 4; ++j)
            lf[(wm * 16 + lg * 4 + j) * 256 + wn * 64 + nn * 16 + lr] = acc[m][nn][j];
        __syncthreads();
#pragma unroll
        for (int k = 0; k < 4; ++k) {
          int idx = tid + k * 512;
          int rl = idx >> 6, c4 = idx & 63;
          int grow = mt * 256 + (rl >> 4) * 128 + m * 16 + (rl & 15);
          if (grow < cnt) {
            *(float4*)&outg[(size_t)(off + grow) * H_DIM + nt * 256 + c4 * 4] =
                *(const float4*)&lf[rl * 256 + c4 * 4];
          }
        }
      }
    }
  }
}

__global__ __launch_bounds__(512, 2) void gemm_gu_kernel(
    const u16* __restrict__ A, const u16* __restrict__ Bmat, void* __restrict__ outp,
    const int* __restrict__ offcnt, int T) {
  gemm8_body<2048, 0>(A, Bmat, outp, offcnt, T);
}

__global__ __launch_bounds__(512, 2) void gemm_down_kernel(
    const u16* __restrict__ A, const u16* __restrict__ Bmat, void* __restrict__ outp,
    const int* __restrict__ offcnt, int T) {
  gemm8_body<1024, 1>(A, Bmat, outp, offcnt, T);
}

extern "C" void kernel_launch(void* const* d_in, const int* in_sizes, int n_in,
                              void* d_out, int out_size, void* d_ws, size_t ws_size,
                              hipStream_t stream) {
  const float* x = (const float*)d_in[0];
  const int* pid = (const int*)d_in[1];
  const float* gup = (const float*)d_in[2];
  const float* dwn = (const float*)d_in[3];
  float* out = (float*)d_out;

  const int T = in_sizes[1];  // 16384

  char* ws = (char*)d_ws;
  size_t o = 0;
  auto take = [&](size_t b) { size_t r = o; o += (b + 255) & ~(size_t)255; return r; };
  int* offcnt = (int*)(ws + take(32 * 4));
  int* hist = (int*)(ws + take(2048 * 4));
  int* base = (int*)(ws + take(2052 * 4));
  int* order = (int*)(ws + take((size_t)T * 4));
  int* pos = (int*)(ws + take((size_t)T * 4));
  u16* xg = (u16*)(ws + take((size_t)T * H_DIM * 2));
  u16* wguT = (u16*)(ws + take((size_t)NEXP * 2048 * 2048 * 2));
  u16* wdT = (u16*)(ws + take((size_t)NEXP * 2048 * 1024 * 2));
  u16* inter = (u16*)(ws + take((size_t)T * EI_DIM * 2));
  // outg (T x 2048 f32 = 128MB) aliases [xg, wguT] (both dead before gemm_down)
  float* outg = (float*)xg;

  hist_kernel<<<T / 64, 64, 0, stream>>>(pid, hist);
  scan_kernel<<<1, 256, 0, stream>>>(hist, base, offcnt, T);
  rank_kernel<<<T / 64, 64, 0, stream>>>(pid, base, order, pos);
  transpose_bf16<<<NEXP * 32 * 32, 256, 0, stream>>>(gup, wguT, 2048, 2048);
  transpose_bf16<<<NEXP * 16 * 32, 256, 0, stream>>>(dwn, wdT, 1024, 2048);
  gather_x<<<T, 256, 0, stream>>>(x, order, xg);

  gemm_gu_kernel<<<512, 512, 0, stream>>>(xg, wguT, inter, offcnt, T);
  gemm_down_kernel<<<512, 512, 0, stream>>>(inter, wdT, outg, offcnt, T);
  unscatter_kernel<<<T, 256, 0, stream>>>(outg, pos, out);
}

// Round 7
// 334.812 us; speedup vs baseline: 1.1199x; 1.1199x over previous
//
#include <hip/hip_runtime.h>
#include <hip/hip_bf16.h>

typedef unsigned short u16;
typedef __attribute__((ext_vector_type(8))) short short8;
typedef __attribute__((ext_vector_type(8))) unsigned short u16x8;
typedef __attribute__((ext_vector_type(4))) float f32x4;

#define H_DIM 2048
#define EI_DIM 1024
#define NEXP 8

template <int V> struct IC { static constexpr int value = V; };

__device__ __forceinline__ u16 f2bf(float f) {
  __hip_bfloat16 h = __float2bfloat16(f);
  return __builtin_bit_cast(unsigned short, h);
}

__device__ __forceinline__ void load_lds16(const void* g, void* lds) {
  __builtin_amdgcn_global_load_lds(
      (const __attribute__((address_space(1))) unsigned int*)g,
      (__attribute__((address_space(3))) unsigned int*)lds, 16, 0, 0);
}

// ---------------- routing ----------------
__global__ void hist_kernel(const int* __restrict__ pid, int* __restrict__ hist) {
  int seg = blockIdx.x, lane = threadIdx.x;
  int eid = pid[seg * 64 + lane] & 7;
#pragma unroll
  for (int e = 0; e < NEXP; ++e) {
    unsigned long long m = __ballot(eid == e);
    if (lane == 0) hist[e * 256 + seg] = __popcll(m);
  }
}

__global__ void scan_kernel(const int* __restrict__ hist, int* __restrict__ base,
                            int* __restrict__ offcnt, int T) {
  __shared__ int lds[256];
  int tid = threadIdx.x;
  int v[8], s = 0;
#pragma unroll
  for (int j = 0; j < 8; ++j) { v[j] = hist[tid * 8 + j]; s += v[j]; }
  lds[tid] = s;
  __syncthreads();
  for (int d = 1; d < 256; d <<= 1) {
    int t = (tid >= d) ? lds[tid - d] : 0;
    __syncthreads();
    lds[tid] += t;
    __syncthreads();
  }
  int run = lds[tid] - s;
#pragma unroll
  for (int j = 0; j < 8; ++j) { base[tid * 8 + j] = run; run += v[j]; }
  __syncthreads();
  if (tid < NEXP) {
    int o = base[tid * 256];
    int nx = (tid < NEXP - 1) ? base[(tid + 1) * 256] : T;
    offcnt[tid] = o;
    offcnt[8 + tid] = nx - o;
  }
}

__global__ void rank_kernel(const int* __restrict__ pid, const int* __restrict__ base,
                            int* __restrict__ order) {
  int seg = blockIdx.x, lane = threadIdx.x;
  int t = seg * 64 + lane;
  int eid = pid[t] & 7;
  unsigned long long below = (1ull << lane) - 1ull;
#pragma unroll
  for (int e = 0; e < NEXP; ++e) {
    unsigned long long m = __ballot(eid == e);
    if (eid == e) {
      int r = __popcll(m & below);
      order[base[e * 256 + seg] + r] = t;
    }
  }
}

// ---------------- weight transpose + fp32->bf16 ----------------
__global__ __launch_bounds__(256) void transpose_bf16(const float* __restrict__ in,
                                                      u16* __restrict__ out, int R, int C) {
  __shared__ u16 tile[64][65];
  int nbr = R >> 6, nbc = C >> 6;
  int per_e = nbr * nbc;
  int bx = blockIdx.x;
  int e = bx / per_e, rem = bx % per_e;
  int tr = rem % nbr, tc = rem / nbr;
  const float* ine = in + (size_t)e * R * C;
  u16* oute = out + (size_t)e * R * C;
  int r0 = tr * 64, c0 = tc * 64;
  int tid = threadIdx.x;
  int lrow = tid >> 4, lc4 = (tid & 15) * 4;
#pragma unroll
  for (int p = 0; p < 4; ++p) {
    int rl = p * 16 + lrow;
    float4 v = *(const float4*)&ine[(size_t)(r0 + rl) * C + c0 + lc4];
    tile[rl][lc4 + 0] = f2bf(v.x);
    tile[rl][lc4 + 1] = f2bf(v.y);
    tile[rl][lc4 + 2] = f2bf(v.z);
    tile[rl][lc4 + 3] = f2bf(v.w);
  }
  __syncthreads();
#pragma unroll
  for (int q = 0; q < 16; ++q) {
    int idx = q * 256 + tid;
    int jr = idx >> 6, hc = idx & 63;
    oute[(size_t)(c0 + jr) * R + r0 + hc] = tile[hc][jr];
  }
}

// ---------------- gather + convert x ----------------
__global__ __launch_bounds__(256) void gather_x(const float* __restrict__ x,
                                                const int* __restrict__ order,
                                                u16* __restrict__ xg) {
  int g = blockIdx.x;
  int t = order[g];
  const float* src = x + (size_t)t * H_DIM;
  u16* dst = xg + (size_t)g * H_DIM;
  int c = threadIdx.x * 8;
  float4 a = *(const float4*)&src[c];
  float4 b = *(const float4*)&src[c + 4];
  u16x8 v;
  v[0] = f2bf(a.x); v[1] = f2bf(a.y); v[2] = f2bf(a.z); v[3] = f2bf(a.w);
  v[4] = f2bf(b.x); v[5] = f2bf(b.y); v[6] = f2bf(b.z); v[7] = f2bf(b.w);
  *(u16x8*)&dst[c] = v;
}

// ---------------- 256x256 8-phase GEMM body, persistent expert-aligned grid ----------------
// grid = 512: XCD x <-> expert x (chunked swizzle); block loops its expert's
// padded item space (64 slots x 8 strides) -> balanced case = 1 real tile/block.
// No sched_barrier inside the phase loop (template-conformant; m141 lesson).
// KIND 0: gu GEMM, gate/up paired cols, fused silu*up -> inter (bf16)
// KIND 1: down GEMM, LDS-staged float4 scatter of fp32 rows to d_out via order[]
template <int KTOT, int KIND>
__device__ __forceinline__ void gemm8_body(
    const u16* __restrict__ A, const u16* __restrict__ Bmat, void* __restrict__ outp,
    const int* __restrict__ offcnt, const int* __restrict__ order, int T) {
  constexpr int NK = KTOT / 64;  // even
  constexpr int ASTR = (KIND == 0) ? H_DIM : EI_DIM;
  constexpr int BSTR = ASTR;
  constexpr size_t BEXP = (size_t)2048 * BSTR;
  __shared__ u16 As[2][2][8192];
  __shared__ u16 Bs[2][2][8192];

  int nwg = gridDim.x;  // 512
  int bid = blockIdx.x;
  int bx = (bid & 7) * (nwg >> 3) + (bid >> 3);  // XCD-chunked, bijective
  int e = bx >> 6;                               // 64 slots per expert
  int s = bx & 63;
  int off = offcnt[e], cnt = offcnt[8 + e];
  const u16* Be = Bmat + (size_t)e * BEXP;

  int tid = threadIdx.x, w = tid >> 6, l = tid & 63;
  int wm = w >> 2, wn = w & 3, lr = l & 15, lg = l >> 4;
  int cidx = (lg ^ ((lr >> 1) & 3)) * 8;  // swizzled 8-elem chunk for ds_read
  int aRow0 = wm * 128 + lr;
  int bRow0 = wn * 64 + lr;
  int sr[2], sc[2];
#pragma unroll
  for (int j = 0; j < 2; ++j) {
    sr[j] = j * 128 + (tid >> 2);
    int c = tid & 3;
    sc[j] = (c ^ ((sr[j] >> 1) & 3)) * 8;
  }

#pragma unroll 1
  for (int it = s; it < 512; it += 64) {
    int mt = it >> 3, nt = it & 7;
    if (mt * 256 >= cnt) continue;

    const u16* aSrc[2];
    const u16* bSrc[2];
#pragma unroll
    for (int j = 0; j < 2; ++j) {
      int r = sr[j];
      int grow = min(off + mt * 256 + r, T - 1);
      aSrc[j] = A + (size_t)grow * ASTR + sc[j];
      int n;
      if (KIND == 0) {
        int q = r >> 4, rr = r & 15;  // pair gate/up at wave granularity
        n = ((q & 2) ? EI_DIM : 0) + nt * 128 + ((q >> 2) << 5) + ((q & 1) << 4) + rr;
      } else {
        n = nt * 256 + r;
      }
      bSrc[j] = Be + (size_t)n * BSTR + sc[j];
    }

    auto stageA = [&](int kt, int kh, int buf) {
#pragma unroll
      for (int j = 0; j < 2; ++j)
        load_lds16(aSrc[j] + kt * 64 + kh * 32, &As[buf][kh][j * 4096 + w * 512]);
    };
    auto stageB = [&](int kt, int kh, int buf) {
#pragma unroll
      for (int j = 0; j < 2; ++j)
        load_lds16(bSrc[j] + kt * 64 + kh * 32, &Bs[buf][kh][j * 4096 + w * 512]);
    };

    short8 av[4], bv[4];
    auto loadA4 = [&](int buf, int kh, int h) {
#pragma unroll
      for (int mm = 0; mm < 4; ++mm)
        av[mm] = *(const short8*)&As[buf][kh][(aRow0 + (h * 4 + mm) * 16) * 32 + cidx];
    };
    auto loadB4 = [&](int buf, int kh) {
#pragma unroll
      for (int nn = 0; nn < 4; ++nn)
        bv[nn] = *(const short8*)&Bs[buf][kh][(bRow0 + nn * 16) * 32 + cidx];
    };

    f32x4 acc[8][4];
#pragma unroll
    for (int m = 0; m < 8; ++m)
#pragma unroll
      for (int nn = 0; nn < 4; ++nn) acc[m][nn] = {0.f, 0.f, 0.f, 0.f};

    auto MFMA_H = [&](auto HC) {
      constexpr int h = decltype(HC)::value;
      __builtin_amdgcn_s_setprio(1);
#pragma unroll
      for (int mm = 0; mm < 4; ++mm)
#pragma unroll
        for (int nn = 0; nn < 4; ++nn)
          acc[h * 4 + mm][nn] =
              __builtin_amdgcn_mfma_f32_16x16x32_bf16(av[mm], bv[nn], acc[h * 4 + mm][nn], 0, 0, 0);
      __builtin_amdgcn_s_setprio(0);
    };

    // protect LDS against previous iteration's readers
    __syncthreads();

    // ---- prologue: tile0 fully + tile1 {Bk0, Ak0, Bk1} ----
    stageA(0, 0, 0); stageB(0, 0, 0); stageA(0, 1, 0); stageB(0, 1, 0);
    stageB(1, 0, 1); stageA(1, 0, 1); stageB(1, 1, 1);
    asm volatile("s_waitcnt vmcnt(6)" ::: "memory");
    __builtin_amdgcn_s_barrier();
    __builtin_amdgcn_sched_barrier(0);

    auto TILE = [&](int t, auto BC) {
      constexpr int b = decltype(BC)::value;
      constexpr int bn = b ^ 1;
      // p1
      loadA4(b, 0, 0);
      loadB4(b, 0);
      stageA(t + 1, 1, bn);
      __builtin_amdgcn_s_barrier();
      MFMA_H(IC<0>{});
      __builtin_amdgcn_s_barrier();
      // p2
      loadA4(b, 0, 1);
      stageB(t + 2, 0, b);
      __builtin_amdgcn_s_barrier();
      MFMA_H(IC<1>{});
      __builtin_amdgcn_s_barrier();
      // p3
      loadA4(b, 1, 0);
      loadB4(b, 1);
      stageA(t + 2, 0, b);
      __builtin_amdgcn_s_barrier();
      MFMA_H(IC<0>{});
      __builtin_amdgcn_s_barrier();
      // p4
      loadA4(b, 1, 1);
      stageB(t + 2, 1, b);
      __builtin_amdgcn_s_barrier();
      MFMA_H(IC<1>{});
      asm volatile("s_waitcnt vmcnt(6)" ::: "memory");
      __builtin_amdgcn_s_barrier();
    };

#pragma unroll 1
    for (int t = 0; t < NK - 3; t += 2) {
      TILE(t, IC<0>{});
      TILE(t + 1, IC<1>{});
    }

    // ---- tail: tile NK-2 (stages only A(NK-1,k1)), drain, tile NK-1 ----
    {
      loadA4(0, 0, 0);
      loadB4(0, 0);
      stageA(NK - 1, 1, 1);
      MFMA_H(IC<0>{});
      loadA4(0, 0, 1);
      MFMA_H(IC<1>{});
      loadA4(0, 1, 0);
      loadB4(0, 1);
      MFMA_H(IC<0>{});
      loadA4(0, 1, 1);
      MFMA_H(IC<1>{});
      asm volatile("s_waitcnt vmcnt(0)" ::: "memory");
      __builtin_amdgcn_s_barrier();
      loadA4(1, 0, 0);
      loadB4(1, 0);
      MFMA_H(IC<0>{});
      loadA4(1, 0, 1);
      MFMA_H(IC<1>{});
      loadA4(1, 1, 0);
      loadB4(1, 1);
      MFMA_H(IC<0>{});
      loadA4(1, 1, 1);
      MFMA_H(IC<1>{});
    }

    // ---- epilogue ----
    if (KIND == 0) {
      u16* inter = (u16*)outp;
#pragma unroll
      for (int m = 0; m < 8; ++m)
#pragma unroll
        for (int nn = 0; nn < 2; ++nn) {
          f32x4 g = acc[m][nn], u = acc[m][nn + 2];
          int icol = nt * 128 + wn * 32 + nn * 16 + lr;
#pragma unroll
          for (int j = 0; j < 4; ++j) {
            int r = wm * 128 + m * 16 + lg * 4 + j;
            int grow = mt * 256 + r;
            if (grow < cnt) {
              float gv = g[j];
              float val = (gv / (1.f + __expf(-gv))) * u[j];
              inter[(size_t)(off + grow) * EI_DIM + icol] = f2bf(val);
            }
          }
        }
    } else {
      // LDS-staged float4 scatter: chunk = 32 rows x 256 cols f32 (32 KB in As)
      float* out = (float*)outp;
      float* lf = (float*)&As[0][0][0];
#pragma unroll
      for (int m = 0; m < 8; ++m) {
        __syncthreads();
#pragma unroll
        for (int nn = 0; nn < 4; ++nn)
#pragma unroll
          for (int j = 0; j < 4; ++j)
            lf[(wm * 16 + lg * 4 + j) * 256 + wn * 64 + nn * 16 + lr] = acc[m][nn][j];
        __syncthreads();
#pragma unroll
        for (int k = 0; k < 4; ++k) {
          int idx = tid + k * 512;
          int rl = idx >> 6, c4 = idx & 63;
          int grow = mt * 256 + (rl >> 4) * 128 + m * 16 + (rl & 15);
          if (grow < cnt) {
            int tt = order[off + grow];
            *(float4*)&out[(size_t)tt * H_DIM + nt * 256 + c4 * 4] =
                *(const float4*)&lf[rl * 256 + c4 * 4];
          }
        }
      }
    }
  }
}

__global__ __launch_bounds__(512, 2) void gemm_gu_kernel(
    const u16* __restrict__ A, const u16* __restrict__ Bmat, void* __restrict__ outp,
    const int* __restrict__ offcnt, int T) {
  gemm8_body<2048, 0>(A, Bmat, outp, offcnt, nullptr, T);
}

__global__ __launch_bounds__(512, 2) void gemm_down_kernel(
    const u16* __restrict__ A, const u16* __restrict__ Bmat, void* __restrict__ outp,
    const int* __restrict__ offcnt, const int* __restrict__ order, int T) {
  gemm8_body<1024, 1>(A, Bmat, outp, offcnt, order, T);
}

extern "C" void kernel_launch(void* const* d_in, const int* in_sizes, int n_in,
                              void* d_out, int out_size, void* d_ws, size_t ws_size,
                              hipStream_t stream) {
  const float* x = (const float*)d_in[0];
  const int* pid = (const int*)d_in[1];
  const float* gup = (const float*)d_in[2];
  const float* dwn = (const float*)d_in[3];
  float* out = (float*)d_out;

  const int T = in_sizes[1];  // 16384

  char* ws = (char*)d_ws;
  size_t o = 0;
  auto take = [&](size_t b) { size_t r = o; o += (b + 255) & ~(size_t)255; return r; };
  int* offcnt = (int*)(ws + take(32 * 4));
  int* hist = (int*)(ws + take(2048 * 4));
  int* base = (int*)(ws + take(2052 * 4));
  int* order = (int*)(ws + take((size_t)T * 4));
  u16* xg = (u16*)(ws + take((size_t)T * H_DIM * 2));
  u16* wguT = (u16*)(ws + take((size_t)NEXP * 2048 * 2048 * 2));
  u16* wdT = (u16*)(ws + take((size_t)NEXP * 2048 * 1024 * 2));
  u16* inter = (u16*)(ws + take((size_t)T * EI_DIM * 2));

  hist_kernel<<<T / 64, 64, 0, stream>>>(pid, hist);
  scan_kernel<<<1, 256, 0, stream>>>(hist, base, offcnt, T);
  rank_kernel<<<T / 64, 64, 0, stream>>>(pid, base, order);
  transpose_bf16<<<NEXP * 32 * 32, 256, 0, stream>>>(gup, wguT, 2048, 2048);
  transpose_bf16<<<NEXP * 16 * 32, 256, 0, stream>>>(dwn, wdT, 1024, 2048);
  gather_x<<<T, 256, 0, stream>>>(x, order, xg);

  gemm_gu_kernel<<<512, 512, 0, stream>>>(xg, wguT, inter, offcnt, T);
  gemm_down_kernel<<<512, 512, 0, stream>>>(inter, wdT, out, offcnt, order, T);
}

// Round 9
// 332.444 us; speedup vs baseline: 1.1279x; 1.0071x over previous
//
#include <hip/hip_runtime.h>
#include <hip/hip_bf16.h>

typedef unsigned short u16;
typedef __attribute__((ext_vector_type(8))) short short8;
typedef __attribute__((ext_vector_type(8))) unsigned short u16x8;
typedef __attribute__((ext_vector_type(4))) float f32x4;

#define H_DIM 2048
#define EI_DIM 1024
#define NEXP 8

template <int V> struct IC { static constexpr int value = V; };

__device__ __forceinline__ u16 f2bf(float f) {
  __hip_bfloat16 h = __float2bfloat16(f);
  return __builtin_bit_cast(unsigned short, h);
}

__device__ __forceinline__ void load_lds16(const void* g, void* lds) {
  __builtin_amdgcn_global_load_lds(
      (const __attribute__((address_space(1))) unsigned int*)g,
      (__attribute__((address_space(3))) unsigned int*)lds, 16, 0, 0);
}

// ---------------- routing ----------------
__global__ void hist_kernel(const int* __restrict__ pid, int* __restrict__ hist) {
  int seg = blockIdx.x, lane = threadIdx.x;
  int eid = pid[seg * 64 + lane] & 7;
#pragma unroll
  for (int e = 0; e < NEXP; ++e) {
    unsigned long long m = __ballot(eid == e);
    if (lane == 0) hist[e * 256 + seg] = __popcll(m);
  }
}

__global__ void scan_kernel(const int* __restrict__ hist, int* __restrict__ base,
                            int* __restrict__ offcnt, int T) {
  __shared__ int lds[256];
  int tid = threadIdx.x;
  int v[8], s = 0;
#pragma unroll
  for (int j = 0; j < 8; ++j) { v[j] = hist[tid * 8 + j]; s += v[j]; }
  lds[tid] = s;
  __syncthreads();
  for (int d = 1; d < 256; d <<= 1) {
    int t = (tid >= d) ? lds[tid - d] : 0;
    __syncthreads();
    lds[tid] += t;
    __syncthreads();
  }
  int run = lds[tid] - s;
#pragma unroll
  for (int j = 0; j < 8; ++j) { base[tid * 8 + j] = run; run += v[j]; }
  __syncthreads();
  if (tid < NEXP) {
    int o = base[tid * 256];
    int nx = (tid < NEXP - 1) ? base[(tid + 1) * 256] : T;
    offcnt[tid] = o;
    offcnt[8 + tid] = nx - o;
  }
}

__global__ void rank_kernel(const int* __restrict__ pid, const int* __restrict__ base,
                            int* __restrict__ order) {
  int seg = blockIdx.x, lane = threadIdx.x;
  int t = seg * 64 + lane;
  int eid = pid[t] & 7;
  unsigned long long below = (1ull << lane) - 1ull;
#pragma unroll
  for (int e = 0; e < NEXP; ++e) {
    unsigned long long m = __ballot(eid == e);
    if (eid == e) {
      int r = __popcll(m & below);
      order[base[e * 256 + seg] + r] = t;
    }
  }
}

// ---------------- weight transpose + fp32->bf16 ----------------
__global__ __launch_bounds__(256) void transpose_bf16(const float* __restrict__ in,
                                                      u16* __restrict__ out, int R, int C) {
  __shared__ u16 tile[64][65];
  int nbr = R >> 6, nbc = C >> 6;
  int per_e = nbr * nbc;
  int bx = blockIdx.x;
  int e = bx / per_e, rem = bx % per_e;
  int tr = rem % nbr, tc = rem / nbr;
  const float* ine = in + (size_t)e * R * C;
  u16* oute = out + (size_t)e * R * C;
  int r0 = tr * 64, c0 = tc * 64;
  int tid = threadIdx.x;
  int lrow = tid >> 4, lc4 = (tid & 15) * 4;
#pragma unroll
  for (int p = 0; p < 4; ++p) {
    int rl = p * 16 + lrow;
    float4 v = *(const float4*)&ine[(size_t)(r0 + rl) * C + c0 + lc4];
    tile[rl][lc4 + 0] = f2bf(v.x);
    tile[rl][lc4 + 1] = f2bf(v.y);
    tile[rl][lc4 + 2] = f2bf(v.z);
    tile[rl][lc4 + 3] = f2bf(v.w);
  }
  __syncthreads();
#pragma unroll
  for (int q = 0; q < 16; ++q) {
    int idx = q * 256 + tid;
    int jr = idx >> 6, hc = idx & 63;
    oute[(size_t)(c0 + jr) * R + r0 + hc] = tile[hc][jr];
  }
}

// ---------------- gather + convert x ----------------
__global__ __launch_bounds__(256) void gather_x(const float* __restrict__ x,
                                                const int* __restrict__ order,
                                                u16* __restrict__ xg) {
  int g = blockIdx.x;
  int t = order[g];
  const float* src = x + (size_t)t * H_DIM;
  u16* dst = xg + (size_t)g * H_DIM;
  int c = threadIdx.x * 8;
  float4 a = *(const float4*)&src[c];
  float4 b = *(const float4*)&src[c + 4];
  u16x8 v;
  v[0] = f2bf(a.x); v[1] = f2bf(a.y); v[2] = f2bf(a.z); v[3] = f2bf(a.w);
  v[4] = f2bf(b.x); v[5] = f2bf(b.y); v[6] = f2bf(b.z); v[7] = f2bf(b.w);
  *(u16x8*)&dst[c] = v;
}

// ---------------- 256x256 8-phase GEMM body, reg-ping-pong pipelined ----------------
// grid = 512: XCD x <-> expert x (chunked swizzle); persistent over expert's item space.
// Fragment regs ping-pong (avA/avB, bvA/bvB); each phase's ds_reads issued one
// phase early into the idle set -> writeback overlaps MFMA (no WAR-on-register
// serialization with the in-flight MFMA cluster).
// KIND 0: gu GEMM, gate/up paired cols, fused silu*up -> inter (bf16)
// KIND 1: down GEMM, LDS-staged float4 scatter of fp32 rows to d_out via order[]
template <int KTOT, int KIND>
__device__ __forceinline__ void gemm8_body(
    const u16* __restrict__ A, const u16* __restrict__ Bmat, void* __restrict__ outp,
    const int* __restrict__ offcnt, const int* __restrict__ order, int T) {
  constexpr int NK = KTOT / 64;  // even, >= 4
  constexpr int ASTR = (KIND == 0) ? H_DIM : EI_DIM;
  constexpr int BSTR = ASTR;
  constexpr size_t BEXP = (size_t)2048 * BSTR;
  __shared__ u16 As[2][2][8192];
  __shared__ u16 Bs[2][2][8192];

  int nwg = gridDim.x;  // 512
  int bid = blockIdx.x;
  int bx = (bid & 7) * (nwg >> 3) + (bid >> 3);  // XCD-chunked, bijective
  int e = bx >> 6;                               // 64 slots per expert
  int s = bx & 63;
  int off = offcnt[e], cnt = offcnt[8 + e];
  const u16* Be = Bmat + (size_t)e * BEXP;

  int tid = threadIdx.x, w = tid >> 6, l = tid & 63;
  int wm = w >> 2, wn = w & 3, lr = l & 15, lg = l >> 4;
  int cidx = (lg ^ ((lr >> 1) & 3)) * 8;  // swizzled 8-elem chunk for ds_read
  int aRow0 = wm * 128 + lr;
  int bRow0 = wn * 64 + lr;
  int sr[2], sc[2];
#pragma unroll
  for (int j = 0; j < 2; ++j) {
    sr[j] = j * 128 + (tid >> 2);
    int c = tid & 3;
    sc[j] = (c ^ ((sr[j] >> 1) & 3)) * 8;
  }

#pragma unroll 1
  for (int it = s; it < 512; it += 64) {
    int mt = it >> 3, nt = it & 7;
    if (mt * 256 >= cnt) continue;

    const u16* aSrc[2];
    const u16* bSrc[2];
#pragma unroll
    for (int j = 0; j < 2; ++j) {
      int r = sr[j];
      int grow = min(off + mt * 256 + r, T - 1);
      aSrc[j] = A + (size_t)grow * ASTR + sc[j];
      int n;
      if (KIND == 0) {
        int q = r >> 4, rr = r & 15;  // pair gate/up at wave granularity
        n = ((q & 2) ? EI_DIM : 0) + nt * 128 + ((q >> 2) << 5) + ((q & 1) << 4) + rr;
      } else {
        n = nt * 256 + r;
      }
      bSrc[j] = Be + (size_t)n * BSTR + sc[j];
    }

    auto stageA = [&](int kt, int kh, int buf) {
#pragma unroll
      for (int j = 0; j < 2; ++j)
        load_lds16(aSrc[j] + kt * 64 + kh * 32, &As[buf][kh][j * 4096 + w * 512]);
    };
    auto stageB = [&](int kt, int kh, int buf) {
#pragma unroll
      for (int j = 0; j < 2; ++j)
        load_lds16(bSrc[j] + kt * 64 + kh * 32, &Bs[buf][kh][j * 4096 + w * 512]);
    };

    short8 avA[4], avB[4], bvA[4], bvB[4];
    auto RDA = [&](short8(&dst)[4], int buf, int kh, int h) {
#pragma unroll
      for (int mm = 0; mm < 4; ++mm)
        dst[mm] = *(const short8*)&As[buf][kh][(aRow0 + (h * 4 + mm) * 16) * 32 + cidx];
    };
    auto RDB = [&](short8(&dst)[4], int buf, int kh) {
#pragma unroll
      for (int nn = 0; nn < 4; ++nn)
        dst[nn] = *(const short8*)&Bs[buf][kh][(bRow0 + nn * 16) * 32 + cidx];
    };

    f32x4 acc[8][4];
#pragma unroll
    for (int m = 0; m < 8; ++m)
#pragma unroll
      for (int nn = 0; nn < 4; ++nn) acc[m][nn] = {0.f, 0.f, 0.f, 0.f};

    auto MF = [&](short8(&a)[4], short8(&b)[4], auto HC) {
      constexpr int h = decltype(HC)::value;
      __builtin_amdgcn_s_setprio(1);
#pragma unroll
      for (int mm = 0; mm < 4; ++mm)
#pragma unroll
        for (int nn = 0; nn < 4; ++nn)
          acc[h * 4 + mm][nn] =
              __builtin_amdgcn_mfma_f32_16x16x32_bf16(a[mm], b[nn], acc[h * 4 + mm][nn], 0, 0, 0);
      __builtin_amdgcn_s_setprio(0);
    };

    // protect LDS against previous iteration's readers
    __syncthreads();

    // ---- prologue: tile0 fully + tile1 {Bk0, Ak0, Bk1} ----
    stageA(0, 0, 0); stageB(0, 0, 0); stageA(0, 1, 0); stageB(0, 1, 0);
    stageB(1, 0, 1); stageA(1, 0, 1); stageB(1, 1, 1);
    asm volatile("s_waitcnt vmcnt(6)" ::: "memory");
    __builtin_amdgcn_s_barrier();
    __builtin_amdgcn_sched_barrier(0);

    // Per tile (buffer b fully landed at tile start):
    // p1: ST A(t+1,1,bn) | MF(avA,bvA,h0) | RD avB<-A[b][0]mh1      | BAR
    // p2: ST B(t+2,0,b)  | MF(avB,bvA,h1) | RD avA<-A[b][1]mh0, bvB | BAR
    // p3: ST A(t+2,0,b)  | MF(avA,bvB,h0) | vmcnt(4) | RD avB mh1   | BAR
    // p4: ST B(t+2,1,b)  | MF(avB,bvB,h1)                            | BAR
    auto TILE = [&](int t, auto BC) {
      constexpr int b = decltype(BC)::value;
      constexpr int bn = b ^ 1;
      RDA(avA, b, 0, 0);
      RDB(bvA, b, 0);
      // p1
      stageA(t + 1, 1, bn);
      MF(avA, bvA, IC<0>{});
      RDA(avB, b, 0, 1);
      __builtin_amdgcn_s_barrier();
      // p2
      stageB(t + 2, 0, b);
      MF(avB, bvA, IC<1>{});
      RDA(avA, b, 1, 0);
      RDB(bvB, b, 1);
      __builtin_amdgcn_s_barrier();
      // p3
      stageA(t + 2, 0, b);
      MF(avA, bvB, IC<0>{});
      asm volatile("s_waitcnt vmcnt(4)" ::: "memory");
      RDA(avB, b, 1, 1);
      __builtin_amdgcn_s_barrier();
      // p4
      stageB(t + 2, 1, b);
      MF(avB, bvB, IC<1>{});
      __builtin_amdgcn_s_barrier();
    };

#pragma unroll 1
    for (int t = 0; t < NK - 3; t += 2) {
      TILE(t, IC<0>{});
      TILE(t + 1, IC<1>{});
    }

    // ---- tail: tile NK-2 (buf0; stages only A(NK-1,k1)); drain; tile NK-1 (buf1) ----
    {
      RDA(avA, 0, 0, 0);
      RDB(bvA, 0, 0);
      stageA(NK - 1, 1, 1);
      MF(avA, bvA, IC<0>{});
      RDA(avB, 0, 0, 1);
      __builtin_amdgcn_s_barrier();
      MF(avB, bvA, IC<1>{});
      RDA(avA, 0, 1, 0);
      RDB(bvB, 0, 1);
      __builtin_amdgcn_s_barrier();
      MF(avA, bvB, IC<0>{});
      asm volatile("s_waitcnt vmcnt(0)" ::: "memory");
      RDA(avB, 0, 1, 1);
      __builtin_amdgcn_s_barrier();
      MF(avB, bvB, IC<1>{});
      __builtin_amdgcn_s_barrier();
      // tile NK-1: no stages, straightline
      RDA(avA, 1, 0, 0);
      RDB(bvA, 1, 0);
      MF(avA, bvA, IC<0>{});
      RDA(avB, 1, 0, 1);
      MF(avB, bvA, IC<1>{});
      RDA(avA, 1, 1, 0);
      RDB(bvB, 1, 1);
      MF(avA, bvB, IC<0>{});
      RDA(avB, 1, 1, 1);
      MF(avB, bvB, IC<1>{});
    }

    // ---- epilogue ----
    if (KIND == 0) {
      u16* inter = (u16*)outp;
#pragma unroll
      for (int m = 0; m < 8; ++m)
#pragma unroll
        for (int nn = 0; nn < 2; ++nn) {
          f32x4 g = acc[m][nn], u = acc[m][nn + 2];
          int icol = nt * 128 + wn * 32 + nn * 16 + lr;
#pragma unroll
          for (int j = 0; j < 4; ++j) {
            int r = wm * 128 + m * 16 + lg * 4 + j;
            int grow = mt * 256 + r;
            if (grow < cnt) {
              float gv = g[j];
              float val = (gv / (1.f + __expf(-gv))) * u[j];
              inter[(size_t)(off + grow) * EI_DIM + icol] = f2bf(val);
            }
          }
        }
    } else {
      // LDS-staged float4 scatter: chunk = 32 rows x 256 cols f32 (32 KB in As)
      float* out = (float*)outp;
      float* lf = (float*)&As[0][0][0];
#pragma unroll
      for (int m = 0; m < 8; ++m) {
        __syncthreads();
#pragma unroll
        for (int nn = 0; nn < 4; ++nn)
#pragma unroll
          for (int j = 0; j < 4; ++j)
            lf[(wm * 16 + lg * 4 + j) * 256 + wn * 64 + nn * 16 + lr] = acc[m][nn][j];
        __syncthreads();
#pragma unroll
        for (int k = 0; k < 4; ++k) {
          int idx = tid + k * 512;
          int rl = idx >> 6, c4 = idx & 63;
          int grow = mt * 256 + (rl >> 4) * 128 + m * 16 + (rl & 15);
          if (grow < cnt) {
            int tt = order[off + grow];
            *(float4*)&out[(size_t)tt * H_DIM + nt * 256 + c4 * 4] =
                *(const float4*)&lf[rl * 256 + c4 * 4];
          }
        }
      }
    }
  }
}

__global__ __launch_bounds__(512, 2) void gemm_gu_kernel(
    const u16* __restrict__ A, const u16* __restrict__ Bmat, void* __restrict__ outp,
    const int* __restrict__ offcnt, int T) {
  gemm8_body<2048, 0>(A, Bmat, outp, offcnt, nullptr, T);
}

__global__ __launch_bounds__(512, 2) void gemm_down_kernel(
    const u16* __restrict__ A, const u16* __restrict__ Bmat, void* __restrict__ outp,
    const int* __restrict__ offcnt, const int* __restrict__ order, int T) {
  gemm8_body<1024, 1>(A, Bmat, outp, offcnt, order, T);
}

extern "C" void kernel_launch(void* const* d_in, const int* in_sizes, int n_in,
                              void* d_out, int out_size, void* d_ws, size_t ws_size,
                              hipStream_t stream) {
  const float* x = (const float*)d_in[0];
  const int* pid = (const int*)d_in[1];
  const float* gup = (const float*)d_in[2];
  const float* dwn = (const float*)d_in[3];
  float* out = (float*)d_out;

  const int T = in_sizes[1];  // 16384

  char* ws = (char*)d_ws;
  size_t o = 0;
  auto take = [&](size_t b) { size_t r = o; o += (b + 255) & ~(size_t)255; return r; };
  int* offcnt = (int*)(ws + take(32 * 4));
  int* hist = (int*)(ws + take(2048 * 4));
  int* base = (int*)(ws + take(2052 * 4));
  int* order = (int*)(ws + take((size_t)T * 4));
  u16* xg = (u16*)(ws + take((size_t)T * H_DIM * 2));
  u16* wguT = (u16*)(ws + take((size_t)NEXP * 2048 * 2048 * 2));
  u16* wdT = (u16*)(ws + take((size_t)NEXP * 2048 * 1024 * 2));
  u16* inter = (u16*)(ws + take((size_t)T * EI_DIM * 2));

  hist_kernel<<<T / 64, 64, 0, stream>>>(pid, hist);
  scan_kernel<<<1, 256, 0, stream>>>(hist, base, offcnt, T);
  rank_kernel<<<T / 64, 64, 0, stream>>>(pid, base, order);
  transpose_bf16<<<NEXP * 32 * 32, 256, 0, stream>>>(gup, wguT, 2048, 2048);
  transpose_bf16<<<NEXP * 16 * 32, 256, 0, stream>>>(dwn, wdT, 1024, 2048);
  gather_x<<<T, 256, 0, stream>>>(x, order, xg);

  gemm_gu_kernel<<<512, 512, 0, stream>>>(xg, wguT, inter, offcnt, T);
  gemm_down_kernel<<<512, 512, 0, stream>>>(inter, wdT, out, offcnt, order, T);
}